// Round 11
// baseline (359.638 us; speedup 1.0000x reference)
//
#include <hip/hip_runtime.h>
#include <hip/hip_bf16.h>

#define N_  100000
#define F_  5
#define D_  128
#define H_  4
#define HD_ 32
#define E_  800000

typedef __attribute__((ext_vector_type(8))) short bf16x8;
typedef __attribute__((ext_vector_type(4))) float f32x4;

__device__ __forceinline__ unsigned short f2bf(float f) {
  unsigned u = __float_as_uint(f);
  u += 0x7FFF + ((u >> 16) & 1);          // round-to-nearest-even
  return (unsigned short)(u >> 16);
}

__device__ __forceinline__ unsigned pk2(float a, float b) {
  __hip_bfloat162 h = __float22bfloat162_rn(make_float2(a, b));  // v_cvt_pk_bf16_f32
  return *(unsigned*)&h;
}

__device__ __forceinline__ float2 bf2f2(unsigned u) {
  float2 r;
  r.x = __uint_as_float(u << 16);
  r.y = __uint_as_float(u & 0xffff0000u);
  return r;
}

// Sum across each 8-lane group (head group when lane owns 4 channels).
__device__ __forceinline__ float rowsum8(float x) {
  x += __int_as_float(__builtin_amdgcn_update_dpp(0, __float_as_int(x), 0x0B1, 0xF, 0xF, false)); // quad_perm [1,0,3,2]
  x += __int_as_float(__builtin_amdgcn_update_dpp(0, __float_as_int(x), 0x04E, 0xF, 0xF, false)); // quad_perm [2,3,0,1]
  x += __int_as_float(__builtin_amdgcn_update_dpp(0, __float_as_int(x), 0x141, 0xF, 0xF, false)); // row_half_mirror
  return x;
}

// ---------------------------------------------------------------------------
// Weight pre-pass: W[k][m] (fp32) -> fragment-tiled bf16 WT. One dispatch for
// all 9 weights; extra blocks zero the degree histogram.
// ---------------------------------------------------------------------------
template<int K, int M>
__device__ __forceinline__ void wconv_one(const float* __restrict__ W,
                                          unsigned short* __restrict__ WT,
                                          int idx) {
  const int r = idx & 7;
  const int l = (idx >> 3) & 15;
  const int rest = idx >> 7;
  const int kq = rest % (K / 8);
  const int i  = rest / (K / 8);
  WT[idx] = f2bf(W[(kq * 8 + r) * M + i * 16 + l]);
}

#define WCONV_NB 480   // 122880 elements / 256
#define SCAN_NB ((N_ + 255) / 256)   // 391

__global__ __launch_bounds__(256) void k_wconv_all(
    const float* __restrict__ w0, const float* __restrict__ w1,
    const float* __restrict__ w2, const float* __restrict__ w3,
    const float* __restrict__ w4, const float* __restrict__ w5,
    const float* __restrict__ w6, const float* __restrict__ w7,
    const float* __restrict__ w8, unsigned short* __restrict__ WT,
    int* __restrict__ deg)
{
  if (blockIdx.x >= WCONV_NB) {
    const int i = (blockIdx.x - WCONV_NB) * 256 + threadIdx.x;
    if (i < N_) deg[i] = 0;
    return;
  }
  const int idx = blockIdx.x * 256 + threadIdx.x;
  if (idx < 8192)        wconv_one<64, 128>(w0, WT,          idx);
  else if (idx < 24576)  wconv_one<128,128>(w1, WT + 8192,   idx - 8192);
  else if (idx < 40960)  wconv_one<128,128>(w2, WT + 24576,  idx - 24576);
  else if (idx < 57344)  wconv_one<128,128>(w3, WT + 40960,  idx - 40960);
  else if (idx < 73728)  wconv_one<128,128>(w4, WT + 57344,  idx - 57344);
  else if (idx < 90112)  wconv_one<128,128>(w5, WT + 73728,  idx - 73728);
  else if (idx < 98304)  wconv_one<128, 64>(w6, WT + 90112,  idx - 90112);
  else if (idx < 106496) wconv_one<64, 128>(w7, WT + 98304,  idx - 98304);
  else                   wconv_one<128,128>(w8, WT + 106496, idx - 106496);
}

// ---------------------------------------------------------------------------
// 64-node-tile GEMM fragments: 4 waves, wave wr owns feature strip
// [wr*(M/4), +M/4). IF = M/64. LDS X tile stride K+8.
// ---------------------------------------------------------------------------
template<int K, int M>
__device__ __forceinline__ void gemm_frag64(const unsigned short* sX,
                                            const unsigned short* __restrict__ WT,
                                            f32x4 (*acc)[4],
                                            int wr, int l16, int kg)
{
  constexpr int SX = K + 8;
  constexpr int IF = M / 64;
  #pragma unroll
  for (int i = 0; i < IF; ++i)
    #pragma unroll
    for (int j = 0; j < 4; ++j) acc[i][j] = (f32x4){0.f, 0.f, 0.f, 0.f};
  #pragma unroll
  for (int k0 = 0; k0 < K; k0 += 32) {
    const int kq = k0 / 8 + kg;
    bf16x8 aw[IF];
    #pragma unroll
    for (int i = 0; i < IF; ++i)
      aw[i] = *(const bf16x8*)&WT[(((wr * IF + i) * (K / 8) + kq) * 16 + l16) * 8];
    #pragma unroll
    for (int j = 0; j < 4; ++j) {
      const bf16x8 bx = *(const bf16x8*)&sX[(j * 16 + l16) * SX + k0 + kg * 8];
      #pragma unroll
      for (int i = 0; i < IF; ++i)
        acc[i][j] = __builtin_amdgcn_mfma_f32_16x16x32_bf16(aw[i], bx, acc[i][j], 0, 0, 0);
    }
  }
}

// acc (+bias, opt relu) -> bf16 LDS tile (64 rows, stride SXO)
template<int M, bool RELU, int SXO>
__device__ __forceinline__ void acc_to_lds64(unsigned short* sY, f32x4 (*acc)[4],
                                             const float* __restrict__ bias,
                                             int wr, int l16, int kg)
{
  constexpr int IF = M / 64;
  float4 b4[IF];
  #pragma unroll
  for (int i = 0; i < IF; ++i)
    b4[i] = *(const float4*)&bias[(wr * IF + i) * 16 + kg * 4];
  #pragma unroll
  for (int j = 0; j < 4; ++j) {
    const int row = j * 16 + l16;
    #pragma unroll
    for (int i = 0; i < IF; ++i) {
      const int f0 = (wr * IF + i) * 16 + kg * 4;
      float ox = acc[i][j][0] + b4[i].x, oy = acc[i][j][1] + b4[i].y;
      float oz = acc[i][j][2] + b4[i].z, ow = acc[i][j][3] + b4[i].w;
      if constexpr (RELU) {
        ox = fmaxf(ox, 0.f); oy = fmaxf(oy, 0.f);
        oz = fmaxf(oz, 0.f); ow = fmaxf(ow, 0.f);
      }
      uint2 p;
      p.x = pk2(ox, oy);
      p.y = pk2(oz, ow);
      *(uint2*)&sY[row * SXO + f0] = p;
    }
  }
}

// ---------------------------------------------------------------------------
// Fused prep MLP + q/k/v/skip projections. 64-node tile, 26.6 KB LDS ->
// 6 blocks/CU co-resident.
// ---------------------------------------------------------------------------
__global__ __launch_bounds__(256) void k_prep_proj(
    const float* __restrict__ x,
    const float* __restrict__ pW1, const float* __restrict__ pb1,
    const unsigned short* __restrict__ wt_p2, const float* __restrict__ pb2,
    const unsigned short* __restrict__ wt_p3, const float* __restrict__ pb3,
    const unsigned short* __restrict__ wt_q, const float* __restrict__ qb,
    const unsigned short* __restrict__ wt_k, const float* __restrict__ kb,
    const unsigned short* __restrict__ wt_v, const float* __restrict__ vb,
    const unsigned short* __restrict__ wt_s, const float* __restrict__ sb,
    unsigned short* __restrict__ q16, unsigned short* __restrict__ k16,
    unsigned short* __restrict__ v16, float* __restrict__ out)
{
  __shared__ __align__(16) unsigned short bufA[64 * 72];    // 64-ch tile
  __shared__ __align__(16) unsigned short bufB[64 * 136];   // 128-ch tile

  const int t = threadIdx.x;
  const int node0 = blockIdx.x * 64;
  const int lane = t & 63;
  const int wr = t >> 6;                 // 4-way feature split
  const int l16 = lane & 15, kg = lane >> 4;

  // ---- stage x (5ch fp32) + W1/b1 into bufB head (dead space pre-t2) ----
  float* sxs = (float*)bufB;          // 320 floats
  float* sw1 = (float*)bufB + 320;    // 320 (W1) + 64 (b1)
  {
    const long gbase = (long)node0 * F_;
    for (int i = t; i < 64 * F_; i += 256) {
      const long g = gbase + i;
      sxs[i] = (g < (long)N_ * F_) ? x[g] : 0.f;
    }
    for (int i = t; i < 384; i += 256)
      sw1[i] = (i < 320) ? pW1[i] : pb1[i - 320];
  }
  __syncthreads();

  // ---- stage1: t1 = relu(x@W1+b1) -> bufA (VALU, K=5); thread owns 16 f ----
  {
    const int n = t >> 2;
    const int f0b = (t & 3) * 16;
    float xr[F_];
    #pragma unroll
    for (int k = 0; k < F_; ++k) xr[k] = sxs[n * F_ + k];
    const float* sb1 = sw1 + 320;
    #pragma unroll
    for (int q = 0; q < 4; ++q) {
      float o[4];
      #pragma unroll
      for (int jj = 0; jj < 4; ++jj) {
        const int f = f0b + q * 4 + jj;
        float a = sb1[f];
        #pragma unroll
        for (int k = 0; k < F_; ++k) a = fmaf(xr[k], sw1[k * 64 + f], a);
        o[jj] = fmaxf(a, 0.f);
      }
      uint2 pkd;
      pkd.x = pk2(o[0], o[1]);
      pkd.y = pk2(o[2], o[3]);
      *(uint2*)&bufA[n * 72 + f0b + q * 4] = pkd;
    }
  }
  __syncthreads();

  f32x4 acc[2][4];

  // ---- stage2: t2 = relu(t1@W2+b2) : K=64 -> M=128, to bufB ----
  gemm_frag64<64, 128>(bufA, wt_p2, acc, wr, l16, kg);
  acc_to_lds64<128, true, 136>(bufB, acc, pb2, wr, l16, kg);   // sxs dead
  __syncthreads();

  // ---- stage3: h = t2@W3+b3 : K=128 -> M=128, overwrite bufB ----
  gemm_frag64<128, 128>(bufB, wt_p3, acc, wr, l16, kg);
  __syncthreads();                      // all reads of t2 complete
  acc_to_lds64<128, false, 136>(bufB, acc, pb3, wr, l16, kg);
  __syncthreads();

  // ---- projections: q,k,v (bf16) ----
  {
    const unsigned short* wtsP[3] = {wt_q, wt_k, wt_v};
    const float* bsP[3] = {qb, kb, vb};
    unsigned short* ysP[3] = {q16, k16, v16};
    #pragma unroll
    for (int ws = 0; ws < 3; ++ws) {
      gemm_frag64<128, 128>(bufB, wtsP[ws], acc, wr, l16, kg);
      const float* __restrict__ bias = bsP[ws];
      unsigned short* __restrict__ Yb = ysP[ws];
      float4 b4[2];
      #pragma unroll
      for (int i = 0; i < 2; ++i)
        b4[i] = *(const float4*)&bias[(wr * 2 + i) * 16 + kg * 4];
      #pragma unroll
      for (int j = 0; j < 4; ++j) {
        const int node = node0 + j * 16 + l16;
        if (node >= N_) continue;
        #pragma unroll
        for (int i = 0; i < 2; ++i) {
          const int f0 = (wr * 2 + i) * 16 + kg * 4;
          uint2 ob;
          ob.x = pk2(acc[i][j][0] + b4[i].x, acc[i][j][1] + b4[i].y);
          ob.y = pk2(acc[i][j][2] + b4[i].z, acc[i][j][3] + b4[i].w);
          *(uint2*)&Yb[(long)node * D_ + f0] = ob;
        }
      }
    }
  }

  // ---- skip projection (fp32 into out) ----
  gemm_frag64<128, 128>(bufB, wt_s, acc, wr, l16, kg);
  {
    float4 b4[2];
    #pragma unroll
    for (int i = 0; i < 2; ++i)
      b4[i] = *(const float4*)&sb[(wr * 2 + i) * 16 + kg * 4];
    #pragma unroll
    for (int j = 0; j < 4; ++j) {
      const int node = node0 + j * 16 + l16;
      if (node >= N_) continue;
      #pragma unroll
      for (int i = 0; i < 2; ++i) {
        const int f0 = (wr * 2 + i) * 16 + kg * 4;
        float4 o = make_float4(acc[i][j][0] + b4[i].x, acc[i][j][1] + b4[i].y,
                               acc[i][j][2] + b4[i].z, acc[i][j][3] + b4[i].w);
        *(float4*)&out[(long)node * D_ + f0] = o;
      }
    }
  }
}

// ---------------------------------------------------------------------------
// CSR build: histogram -> scan -> fill. scan23 also packs meta=(start,deg).
// ---------------------------------------------------------------------------
__global__ __launch_bounds__(256) void k_hist(const int* __restrict__ ei,
                                              int* __restrict__ deg) {
  int e = blockIdx.x * 256 + threadIdx.x;
  if (e < E_) atomicAdd(&deg[ei[E_ + e]], 1);
}

__global__ __launch_bounds__(256) void k_scan1(const int* __restrict__ deg,
                                               int* __restrict__ off,
                                               int* __restrict__ bsum) {
  __shared__ int s[256];
  const int t = threadIdx.x;
  const int i = blockIdx.x * 256 + t;
  const int v = (i < N_) ? deg[i] : 0;
  s[t] = v;
  __syncthreads();
  #pragma unroll
  for (int o = 1; o < 256; o <<= 1) {
    int u = (t >= o) ? s[t - o] : 0;
    __syncthreads();
    s[t] += u;
    __syncthreads();
  }
  if (i < N_) off[i] = s[t] - v;
  if (t == 255) bsum[blockIdx.x] = s[255];
}

// scan2 folded in: each block reduces its own prefix of bsum (<=391 ints, L2)
__global__ __launch_bounds__(256) void k_scan23(const int* __restrict__ off,
                                                const int* __restrict__ bsum,
                                                int* __restrict__ cur,
                                                const int* __restrict__ deg,
                                                int2* __restrict__ meta) {
  __shared__ int sacc[256];
  const int t = threadIdx.x;
  const int bid = blockIdx.x;
  int s = 0;
  for (int j = t; j < bid; j += 256) s += bsum[j];
  sacc[t] = s;
  __syncthreads();
  #pragma unroll
  for (int o = 128; o > 0; o >>= 1) {
    if (t < o) sacc[t] += sacc[t + o];
    __syncthreads();
  }
  const int prefix = sacc[0];
  const int i = bid * 256 + t;
  if (i < N_) {
    const int o = off[i] + prefix;
    cur[i] = o;
    meta[i] = make_int2(o, deg[i]);
  }
}

__global__ __launch_bounds__(256) void k_fill(const int* __restrict__ ei,
                                              int* __restrict__ cur,
                                              int* __restrict__ esrc) {
  int e = blockIdx.x * 256 + threadIdx.x;
  if (e < E_) {
    int src = ei[e], dst = ei[E_ + e];
    int pos = atomicAdd(&cur[dst], 1);
    esrc[pos] = src;
  }
}

// ---------------------------------------------------------------------------
// FUSED attention + update MLP. One 64-node tile per block (grid 1563).
// Phase A: 8 half-waves x 8 nodes each run the R8-proven attn inner loop
// (32-lane half, split K/V, uint2 loads, 2 edges/iter, data prefetch 1 deep,
// index 2 deep); h = skip + attn is written to out (fp32, for exact residual,
// L2-warm for phase B) AND as bf16 directly into LDS bufB (deletes update's
// 50MB stage read). Phase B: u1/u2/u3 on the LDS tile; u3 residual-reads the
// L2-warm h and overwrites out with the final result.
// ---------------------------------------------------------------------------
__global__ __launch_bounds__(256) void k_attn_update(
    const int* __restrict__ esrc, const int2* __restrict__ meta,
    const unsigned short* __restrict__ q,
    const unsigned short* __restrict__ kbuf,
    const unsigned short* __restrict__ vbuf,
    const unsigned short* __restrict__ wt_u1, const float* __restrict__ ub1,
    const unsigned short* __restrict__ wt_u2, const float* __restrict__ ub2,
    const unsigned short* __restrict__ wt_u3, const float* __restrict__ ub3,
    float* __restrict__ out)
{
  __shared__ __align__(16) unsigned short bufA[64 * 72];
  __shared__ __align__(16) unsigned short bufB[64 * 136];

  const int t = threadIdx.x;
  const int node0 = blockIdx.x * 64;
  const int half = t >> 5;               // 0..7: owns rows half*8 .. half*8+7
  const int c = t & 31;                  // channels 4c..4c+3
  const float C = 0.17677669529663687f * 1.4426950408889634f; // scale*log2e

  // ================= Phase A: attention for this block's 64 nodes ==========
  for (int s = 0; s < 8; ++s) {
    const int row = half * 8 + s;
    const int node = node0 + row;
    if (node >= N_) {                    // tail: zero the LDS row
      *(uint2*)&bufB[row * 136 + 4 * c] = make_uint2(0u, 0u);
      continue;
    }

    const int2 md = meta[node];
    const int start = md.x, cnt = md.y;
    const int end = start + cnt;

    const uint2 qu = *(const uint2*)&q[((unsigned)node << 7) + 4u * c];
    const float2 q01 = bf2f2(qu.x), q23 = bf2f2(qu.y);
    const float qx0 = q01.x * C, qx1 = q01.y * C;
    const float qx2 = q23.x * C, qx3 = q23.y * C;

    float l = 0.f, a0 = 0.f, a1 = 0.f, a2 = 0.f, a3 = 0.f;

    const int P = (cnt + 1) >> 1;        // 2 edges per iteration
    if (P > 0) {
      bool v1c = (start + 1) < end;
      unsigned i0 = esrc[start];
      unsigned i1 = esrc[v1c ? start + 1 : start];
      uint2 kA = *(const uint2*)&kbuf[((long)i0 << 7) + 4u * c];
      uint2 kB = *(const uint2*)&kbuf[((long)i1 << 7) + 4u * c];
      uint2 wA = *(const uint2*)&vbuf[((long)i0 << 7) + 4u * c];
      uint2 wB = *(const uint2*)&vbuf[((long)i1 << 7) + 4u * c];
      bool v0n = (start + 2) < end, v1n = (start + 3) < end;
      unsigned i0n = esrc[v0n ? start + 2 : start];
      unsigned i1n = esrc[v1n ? start + 3 : start];

      for (int it = 0;;) {
        const bool more = (it + 1) < P;
        uint2 kAn, kBn, wAn, wBn;
        unsigned i0f = 0, i1f = 0;
        bool v0f = false, v1f = false;
        if (more) {                      // prefetch: data it+1, indices it+2
          kAn = *(const uint2*)&kbuf[((long)i0n << 7) + 4u * c];
          kBn = *(const uint2*)&kbuf[((long)i1n << 7) + 4u * c];
          wAn = *(const uint2*)&vbuf[((long)i0n << 7) + 4u * c];
          wBn = *(const uint2*)&vbuf[((long)i1n << 7) + 4u * c];
          const int ef = start + 2 * (it + 2);
          v0f = ef < end; v1f = (ef + 1) < end;
          i0f = esrc[v0f ? ef : start];
          i1f = esrc[v1f ? ef + 1 : start];
        }

        const float2 ka01 = bf2f2(kA.x), ka23 = bf2f2(kA.y);
        const float2 kb01 = bf2f2(kB.x), kb23 = bf2f2(kB.y);
        float sA = fmaf(qx0, ka01.x, fmaf(qx1, ka01.y, fmaf(qx2, ka23.x, qx3 * ka23.y)));
        float sB = fmaf(qx0, kb01.x, fmaf(qx1, kb01.y, fmaf(qx2, kb23.x, qx3 * kb23.y)));
        sA = rowsum8(sA);
        sB = rowsum8(sB);
        const float eA = __builtin_amdgcn_exp2f(sA);
        const float eB = v1c ? __builtin_amdgcn_exp2f(sB) : 0.f;
        const float2 va01 = bf2f2(wA.x), va23 = bf2f2(wA.y);
        const float2 vb01 = bf2f2(wB.x), vb23 = bf2f2(wB.y);
        l += eA + eB;
        a0 = fmaf(eA, va01.x, fmaf(eB, vb01.x, a0));
        a1 = fmaf(eA, va01.y, fmaf(eB, vb01.y, a1));
        a2 = fmaf(eA, va23.x, fmaf(eB, vb23.x, a2));
        a3 = fmaf(eA, va23.y, fmaf(eB, vb23.y, a3));

        if (!more) break;
        ++it;
        kA = kAn; kB = kBn; wA = wAn; wB = wBn;
        v1c = v1n;
        v0n = v0f; v1n = v1f;
        i0n = i0f; i1n = i1f;
      }
    }

    float r0 = 0.f, r1 = 0.f, r2 = 0.f, r3 = 0.f;
    if (l > 0.f) {
      const float inv = 1.0f / l;
      r0 = a0 * inv; r1 = a1 * inv; r2 = a2 * inv; r3 = a3 * inv;
    }

    // h = skip + attn: fp32 to out (residual source), bf16 to LDS (MLP input)
    float4* op = (float4*)&out[((unsigned)node << 7) + 4u * c];
    float4 sk = *op;
    const float h0 = sk.x + r0, h1 = sk.y + r1;
    const float h2 = sk.z + r2, h3 = sk.w + r3;
    *op = make_float4(h0, h1, h2, h3);
    uint2 hb;
    hb.x = pk2(h0, h1);
    hb.y = pk2(h2, h3);
    *(uint2*)&bufB[row * 136 + 4 * c] = hb;
  }
  __syncthreads();

  // ================= Phase B: update MLP on the LDS tile ===================
  const int lane = t & 63;
  const int wr = t >> 6;
  const int l16 = lane & 15, kg = lane >> 4;

  f32x4 acc[2][4];

  // ---- u1: K=128 -> M=64, relu, to bufA ----
  gemm_frag64<128, 64>(bufB, wt_u1, acc, wr, l16, kg);
  acc_to_lds64<64, true, 72>(bufA, acc, ub1, wr, l16, kg);
  __syncthreads();

  // ---- u2: K=64 -> M=128, relu, to bufB (h-bf16 dead after u1) ----
  gemm_frag64<64, 128>(bufA, wt_u2, acc, wr, l16, kg);
  acc_to_lds64<128, true, 136>(bufB, acc, ub2, wr, l16, kg);
  __syncthreads();

  // ---- u3: K=128 -> M=128 + bias + residual(out, L2-warm) -> out ----
  gemm_frag64<128, 128>(bufB, wt_u3, acc, wr, l16, kg);
  {
    float4 b4[2];
    #pragma unroll
    for (int i = 0; i < 2; ++i)
      b4[i] = *(const float4*)&ub3[(wr * 2 + i) * 16 + kg * 4];
    #pragma unroll
    for (int j = 0; j < 4; ++j) {
      const int node = node0 + j * 16 + l16;
      if (node >= N_) continue;
      #pragma unroll
      for (int i = 0; i < 2; ++i) {
        const int f0 = (wr * 2 + i) * 16 + kg * 4;
        const float4 r = *(const float4*)&out[(long)node * D_ + f0];
        float4 o = make_float4(acc[i][j][0] + b4[i].x + r.x,
                               acc[i][j][1] + b4[i].y + r.y,
                               acc[i][j][2] + b4[i].z + r.z,
                               acc[i][j][3] + b4[i].w + r.w);
        *(float4*)&out[(long)node * D_ + f0] = o;
      }
    }
  }
}

// ---------------------------------------------------------------------------
extern "C" void kernel_launch(void* const* d_in, const int* in_sizes, int n_in,
                              void* d_out, int out_size, void* d_ws, size_t ws_size,
                              hipStream_t stream) {
  const float* x   = (const float*)d_in[0];
  const int*   ei  = (const int*)d_in[1];
  const float* pW1 = (const float*)d_in[2];  const float* pb1 = (const float*)d_in[3];
  const float* pW2 = (const float*)d_in[4];  const float* pb2 = (const float*)d_in[5];
  const float* pW3 = (const float*)d_in[6];  const float* pb3 = (const float*)d_in[7];
  const float* uW1 = (const float*)d_in[8];  const float* ub1 = (const float*)d_in[9];
  const float* uW2 = (const float*)d_in[10]; const float* ub2 = (const float*)d_in[11];
  const float* uW3 = (const float*)d_in[12]; const float* ub3 = (const float*)d_in[13];
  const float* qW  = (const float*)d_in[14]; const float* qb  = (const float*)d_in[15];
  const float* kW  = (const float*)d_in[16]; const float* kb  = (const float*)d_in[17];
  const float* vW  = (const float*)d_in[18]; const float* vb  = (const float*)d_in[19];
  const float* sW  = (const float*)d_in[20]; const float* sb  = (const float*)d_in[21];

  float* out = (float*)d_out;
  float* ws  = (float*)d_ws;

  const long ND = (long)N_ * D_;
  // regions (ND floats each): 0=CSR overlay, 1=q, 2=k, 3=v; 4=weights
  unsigned short* q16 = (unsigned short*)(ws + ND);
  unsigned short* k16 = (unsigned short*)(ws + 2 * ND);
  unsigned short* v16 = (unsigned short*)(ws + 3 * ND);

  unsigned short* wtb = (unsigned short*)(ws + 4 * ND);
  unsigned short* wt_p2 = wtb;            // 64x128
  unsigned short* wt_p3 = wtb + 8192;     // 128x128
  unsigned short* wt_q  = wtb + 24576;
  unsigned short* wt_k  = wtb + 40960;
  unsigned short* wt_v  = wtb + 57344;
  unsigned short* wt_s  = wtb + 73728;
  unsigned short* wt_u1 = wtb + 90112;    // 128x64
  unsigned short* wt_u2 = wtb + 98304;    // 64x128
  unsigned short* wt_u3 = wtb + 106496;   // 128x128

  // CSR overlays in region 0
  int* deg  = (int*)ws;
  int* off  = deg + N_;
  int* cur  = off + N_;
  int* esrc = cur + N_;
  int* bsum = esrc + E_;
  int2* meta = (int2*)(bsum + 512);       // 8B-aligned

  const int gT64 = (N_ + 63) / 64;    // 1563

  // --- weight conversion + deg zeroing (one dispatch) ---
  k_wconv_all<<<WCONV_NB + SCAN_NB, 256, 0, stream>>>(
      pW2, pW3, qW, kW, vW, sW, uW1, uW2, uW3, wtb, deg);

  // --- CSR build (split kernels; R6's grid-barrier fusion was 20x slower) ---
  k_hist  <<<(E_ + 255) / 256, 256, 0, stream>>>(ei, deg);
  k_scan1 <<<SCAN_NB, 256, 0, stream>>>(deg, off, bsum);
  k_scan23<<<SCAN_NB, 256, 0, stream>>>(off, bsum, cur, deg, meta);
  k_fill  <<<(E_ + 255) / 256, 256, 0, stream>>>(ei, cur, esrc);

  // --- fused prep MLP + projections: x -> q,k,v (bf16) + skip (fp32 in out) ---
  k_prep_proj<<<gT64, 256, 0, stream>>>(
      x, pW1, pb1, wt_p2, pb2, wt_p3, pb3,
      wt_q, qb, wt_k, kb, wt_v, vb, wt_s, sb,
      q16, k16, v16, out);

  // --- FUSED attention + update MLP: out = h + mlp(h), h = skip + attn ---
  k_attn_update<<<gT64, 256, 0, stream>>>(
      esrc, meta, q16, k16, v16,
      wt_u1, ub1, wt_u2, ub2, wt_u3, ub3, out);
}

// Round 12
// 314.861 us; speedup vs baseline: 1.1422x; 1.1422x over previous
//
#include <hip/hip_runtime.h>
#include <hip/hip_bf16.h>

#define N_  100000
#define F_  5
#define D_  128
#define H_  4
#define HD_ 32
#define E_  800000

typedef __attribute__((ext_vector_type(8))) short bf16x8;
typedef __attribute__((ext_vector_type(4))) float f32x4;

__device__ __forceinline__ unsigned short f2bf(float f) {
  unsigned u = __float_as_uint(f);
  u += 0x7FFF + ((u >> 16) & 1);          // round-to-nearest-even
  return (unsigned short)(u >> 16);
}

__device__ __forceinline__ unsigned pk2(float a, float b) {
  __hip_bfloat162 h = __float22bfloat162_rn(make_float2(a, b));  // v_cvt_pk_bf16_f32
  return *(unsigned*)&h;
}

__device__ __forceinline__ float2 bf2f2(unsigned u) {
  float2 r;
  r.x = __uint_as_float(u << 16);
  r.y = __uint_as_float(u & 0xffff0000u);
  return r;
}

// Sum across each 8-lane group (head group when lane owns 4 channels).
__device__ __forceinline__ float rowsum8(float x) {
  x += __int_as_float(__builtin_amdgcn_update_dpp(0, __float_as_int(x), 0x0B1, 0xF, 0xF, false)); // quad_perm [1,0,3,2]
  x += __int_as_float(__builtin_amdgcn_update_dpp(0, __float_as_int(x), 0x04E, 0xF, 0xF, false)); // quad_perm [2,3,0,1]
  x += __int_as_float(__builtin_amdgcn_update_dpp(0, __float_as_int(x), 0x141, 0xF, 0xF, false)); // row_half_mirror
  return x;
}

// ---------------------------------------------------------------------------
// Weight conversion fragments
// ---------------------------------------------------------------------------
template<int K, int M>
__device__ __forceinline__ void wconv_one(const float* __restrict__ W,
                                          unsigned short* __restrict__ WT,
                                          int idx) {
  const int r = idx & 7;
  const int l = (idx >> 3) & 15;
  const int rest = idx >> 7;
  const int kq = rest % (K / 8);
  const int i  = rest / (K / 8);
  WT[idx] = f2bf(W[(kq * 8 + r) * M + i * 16 + l]);
}

#define WCONV_NB 480   // 122880 elements / 256
#define HIST_NB  ((E_ + 255) / 256)  // 3125
#define SCAN_NB  ((N_ + 255) / 256)  // 391

// ---------------------------------------------------------------------------
// Block-range fused: weight conversion (480 blocks) || degree histogram
// (3125 blocks). Independent work, whole-block uniform branch. deg is
// zeroed by hipMemsetAsync before this dispatch.
// ---------------------------------------------------------------------------
__global__ __launch_bounds__(256) void k_wconv_hist(
    const float* __restrict__ w0, const float* __restrict__ w1,
    const float* __restrict__ w2, const float* __restrict__ w3,
    const float* __restrict__ w4, const float* __restrict__ w5,
    const float* __restrict__ w6, const float* __restrict__ w7,
    const float* __restrict__ w8, unsigned short* __restrict__ WT,
    const int* __restrict__ ei, int* __restrict__ deg)
{
  if (blockIdx.x >= WCONV_NB) {
    const int e = (blockIdx.x - WCONV_NB) * 256 + threadIdx.x;
    if (e < E_) atomicAdd(&deg[ei[E_ + e]], 1);
    return;
  }
  const int idx = blockIdx.x * 256 + threadIdx.x;
  if (idx < 8192)        wconv_one<64, 128>(w0, WT,          idx);
  else if (idx < 24576)  wconv_one<128,128>(w1, WT + 8192,   idx - 8192);
  else if (idx < 40960)  wconv_one<128,128>(w2, WT + 24576,  idx - 24576);
  else if (idx < 57344)  wconv_one<128,128>(w3, WT + 40960,  idx - 40960);
  else if (idx < 73728)  wconv_one<128,128>(w4, WT + 57344,  idx - 57344);
  else if (idx < 90112)  wconv_one<128,128>(w5, WT + 73728,  idx - 73728);
  else if (idx < 98304)  wconv_one<128, 64>(w6, WT + 90112,  idx - 90112);
  else if (idx < 106496) wconv_one<64, 128>(w7, WT + 98304,  idx - 98304);
  else                   wconv_one<128,128>(w8, WT + 106496, idx - 106496);
}

// ---------------------------------------------------------------------------
// 64-node-tile GEMM fragments: 4 waves, wave wr owns feature strip
// [wr*(M/4), +M/4). IF = M/64. LDS X tile stride K+8.
// ---------------------------------------------------------------------------
template<int K, int M>
__device__ __forceinline__ void gemm_frag64(const unsigned short* sX,
                                            const unsigned short* __restrict__ WT,
                                            f32x4 (*acc)[4],
                                            int wr, int l16, int kg)
{
  constexpr int SX = K + 8;
  constexpr int IF = M / 64;
  #pragma unroll
  for (int i = 0; i < IF; ++i)
    #pragma unroll
    for (int j = 0; j < 4; ++j) acc[i][j] = (f32x4){0.f, 0.f, 0.f, 0.f};
  #pragma unroll
  for (int k0 = 0; k0 < K; k0 += 32) {
    const int kq = k0 / 8 + kg;
    bf16x8 aw[IF];
    #pragma unroll
    for (int i = 0; i < IF; ++i)
      aw[i] = *(const bf16x8*)&WT[(((wr * IF + i) * (K / 8) + kq) * 16 + l16) * 8];
    #pragma unroll
    for (int j = 0; j < 4; ++j) {
      const bf16x8 bx = *(const bf16x8*)&sX[(j * 16 + l16) * SX + k0 + kg * 8];
      #pragma unroll
      for (int i = 0; i < IF; ++i)
        acc[i][j] = __builtin_amdgcn_mfma_f32_16x16x32_bf16(aw[i], bx, acc[i][j], 0, 0, 0);
    }
  }
}

// acc (+bias, opt relu) -> bf16 LDS tile (64 rows, stride SXO)
template<int M, bool RELU, int SXO>
__device__ __forceinline__ void acc_to_lds64(unsigned short* sY, f32x4 (*acc)[4],
                                             const float* __restrict__ bias,
                                             int wr, int l16, int kg)
{
  constexpr int IF = M / 64;
  float4 b4[IF];
  #pragma unroll
  for (int i = 0; i < IF; ++i)
    b4[i] = *(const float4*)&bias[(wr * IF + i) * 16 + kg * 4];
  #pragma unroll
  for (int j = 0; j < 4; ++j) {
    const int row = j * 16 + l16;
    #pragma unroll
    for (int i = 0; i < IF; ++i) {
      const int f0 = (wr * IF + i) * 16 + kg * 4;
      float ox = acc[i][j][0] + b4[i].x, oy = acc[i][j][1] + b4[i].y;
      float oz = acc[i][j][2] + b4[i].z, ow = acc[i][j][3] + b4[i].w;
      if constexpr (RELU) {
        ox = fmaxf(ox, 0.f); oy = fmaxf(oy, 0.f);
        oz = fmaxf(oz, 0.f); ow = fmaxf(ow, 0.f);
      }
      uint2 p;
      p.x = pk2(ox, oy);
      p.y = pk2(oz, ow);
      *(uint2*)&sY[row * SXO + f0] = p;
    }
  }
}

// ---------------------------------------------------------------------------
// CSR scans (hist -> scan1 -> scan23). scan23 also packs meta=(start,deg).
// ---------------------------------------------------------------------------
__global__ __launch_bounds__(256) void k_scan1(const int* __restrict__ deg,
                                               int* __restrict__ off,
                                               int* __restrict__ bsum) {
  __shared__ int s[256];
  const int t = threadIdx.x;
  const int i = blockIdx.x * 256 + t;
  const int v = (i < N_) ? deg[i] : 0;
  s[t] = v;
  __syncthreads();
  #pragma unroll
  for (int o = 1; o < 256; o <<= 1) {
    int u = (t >= o) ? s[t - o] : 0;
    __syncthreads();
    s[t] += u;
    __syncthreads();
  }
  if (i < N_) off[i] = s[t] - v;
  if (t == 255) bsum[blockIdx.x] = s[255];
}

__global__ __launch_bounds__(256) void k_scan23(const int* __restrict__ off,
                                                const int* __restrict__ bsum,
                                                int* __restrict__ cur,
                                                const int* __restrict__ deg,
                                                int2* __restrict__ meta) {
  __shared__ int sacc[256];
  const int t = threadIdx.x;
  const int bid = blockIdx.x;
  int s = 0;
  for (int j = t; j < bid; j += 256) s += bsum[j];
  sacc[t] = s;
  __syncthreads();
  #pragma unroll
  for (int o = 128; o > 0; o >>= 1) {
    if (t < o) sacc[t] += sacc[t + o];
    __syncthreads();
  }
  const int prefix = sacc[0];
  const int i = bid * 256 + t;
  if (i < N_) {
    const int o = off[i] + prefix;
    cur[i] = o;
    meta[i] = make_int2(o, deg[i]);
  }
}

// ---------------------------------------------------------------------------
// Block-range fused: CSR fill (3125 blocks, latency/atomic-bound) || prep MLP
// + q/k/v/skip projections (1563 blocks, MFMA-bound). Interleaved 2:1 so both
// types co-reside on each CU: fill's stalls hide under prep's compute.
// Dependencies: fill needs scan23 (cur); prep needs wconv (done). Outputs
// disjoint. Whole-block uniform branch.
// ---------------------------------------------------------------------------
__global__ __launch_bounds__(256) void k_fill_prep(
    const int* __restrict__ ei, int* __restrict__ cur, int* __restrict__ esrc,
    const float* __restrict__ x,
    const float* __restrict__ pW1, const float* __restrict__ pb1,
    const unsigned short* __restrict__ wt_p2, const float* __restrict__ pb2,
    const unsigned short* __restrict__ wt_p3, const float* __restrict__ pb3,
    const unsigned short* __restrict__ wt_q, const float* __restrict__ qb,
    const unsigned short* __restrict__ wt_k, const float* __restrict__ kb,
    const unsigned short* __restrict__ wt_v, const float* __restrict__ vb,
    const unsigned short* __restrict__ wt_s, const float* __restrict__ sb,
    unsigned short* __restrict__ q16, unsigned short* __restrict__ k16,
    unsigned short* __restrict__ v16, float* __restrict__ out)
{
  __shared__ __align__(16) unsigned short bufA[64 * 72];    // 64-ch tile
  __shared__ __align__(16) unsigned short bufB[64 * 136];   // 128-ch tile

  const int bmod = blockIdx.x % 3;
  if (bmod != 2) {
    // ---------------- fill path (2 of every 3 blocks) ----------------
    const int fid = (blockIdx.x / 3) * 2 + bmod;   // 0..3125 (3125 no-ops)
    const int e = fid * 256 + threadIdx.x;
    if (e < E_) {
      const int src = ei[e], dst = ei[E_ + e];
      const int pos = atomicAdd(&cur[dst], 1);
      esrc[pos] = src;
    }
    return;
  }

  // ---------------- prep path (1 of every 3 blocks) ----------------
  const int t = threadIdx.x;
  const int node0 = (blockIdx.x / 3) * 64;         // 0..1562 tiles
  const int lane = t & 63;
  const int wr = t >> 6;                 // 4-way feature split
  const int l16 = lane & 15, kg = lane >> 4;

  // ---- stage x (5ch fp32) + W1/b1 into bufB head (dead space pre-t2) ----
  float* sxs = (float*)bufB;          // 320 floats
  float* sw1 = (float*)bufB + 320;    // 320 (W1) + 64 (b1)
  {
    const long gbase = (long)node0 * F_;
    for (int i = t; i < 64 * F_; i += 256) {
      const long g = gbase + i;
      sxs[i] = (g < (long)N_ * F_) ? x[g] : 0.f;
    }
    for (int i = t; i < 384; i += 256)
      sw1[i] = (i < 320) ? pW1[i] : pb1[i - 320];
  }
  __syncthreads();

  // ---- stage1: t1 = relu(x@W1+b1) -> bufA (VALU, K=5); thread owns 16 f ----
  {
    const int n = t >> 2;
    const int f0b = (t & 3) * 16;
    float xr[F_];
    #pragma unroll
    for (int k = 0; k < F_; ++k) xr[k] = sxs[n * F_ + k];
    const float* sb1 = sw1 + 320;
    #pragma unroll
    for (int q = 0; q < 4; ++q) {
      float o[4];
      #pragma unroll
      for (int jj = 0; jj < 4; ++jj) {
        const int f = f0b + q * 4 + jj;
        float a = sb1[f];
        #pragma unroll
        for (int k = 0; k < F_; ++k) a = fmaf(xr[k], sw1[k * 64 + f], a);
        o[jj] = fmaxf(a, 0.f);
      }
      uint2 pkd;
      pkd.x = pk2(o[0], o[1]);
      pkd.y = pk2(o[2], o[3]);
      *(uint2*)&bufA[n * 72 + f0b + q * 4] = pkd;
    }
  }
  __syncthreads();

  f32x4 acc[2][4];

  // ---- stage2: t2 = relu(t1@W2+b2) : K=64 -> M=128, to bufB ----
  gemm_frag64<64, 128>(bufA, wt_p2, acc, wr, l16, kg);
  acc_to_lds64<128, true, 136>(bufB, acc, pb2, wr, l16, kg);   // sxs dead
  __syncthreads();

  // ---- stage3: h = t2@W3+b3 : K=128 -> M=128, overwrite bufB ----
  gemm_frag64<128, 128>(bufB, wt_p3, acc, wr, l16, kg);
  __syncthreads();                      // all reads of t2 complete
  acc_to_lds64<128, false, 136>(bufB, acc, pb3, wr, l16, kg);
  __syncthreads();

  // ---- projections: q,k,v (bf16) ----
  {
    const unsigned short* wtsP[3] = {wt_q, wt_k, wt_v};
    const float* bsP[3] = {qb, kb, vb};
    unsigned short* ysP[3] = {q16, k16, v16};
    #pragma unroll
    for (int ws = 0; ws < 3; ++ws) {
      gemm_frag64<128, 128>(bufB, wtsP[ws], acc, wr, l16, kg);
      const float* __restrict__ bias = bsP[ws];
      unsigned short* __restrict__ Yb = ysP[ws];
      float4 b4[2];
      #pragma unroll
      for (int i = 0; i < 2; ++i)
        b4[i] = *(const float4*)&bias[(wr * 2 + i) * 16 + kg * 4];
      #pragma unroll
      for (int j = 0; j < 4; ++j) {
        const int node = node0 + j * 16 + l16;
        if (node >= N_) continue;
        #pragma unroll
        for (int i = 0; i < 2; ++i) {
          const int f0 = (wr * 2 + i) * 16 + kg * 4;
          uint2 ob;
          ob.x = pk2(acc[i][j][0] + b4[i].x, acc[i][j][1] + b4[i].y);
          ob.y = pk2(acc[i][j][2] + b4[i].z, acc[i][j][3] + b4[i].w);
          *(uint2*)&Yb[(long)node * D_ + f0] = ob;
        }
      }
    }
  }

  // ---- skip projection (fp32 into out) ----
  gemm_frag64<128, 128>(bufB, wt_s, acc, wr, l16, kg);
  {
    float4 b4[2];
    #pragma unroll
    for (int i = 0; i < 2; ++i)
      b4[i] = *(const float4*)&sb[(wr * 2 + i) * 16 + kg * 4];
    #pragma unroll
    for (int j = 0; j < 4; ++j) {
      const int node = node0 + j * 16 + l16;
      if (node >= N_) continue;
      #pragma unroll
      for (int i = 0; i < 2; ++i) {
        const int f0 = (wr * 2 + i) * 16 + kg * 4;
        float4 o = make_float4(acc[i][j][0] + b4[i].x, acc[i][j][1] + b4[i].y,
                               acc[i][j][2] + b4[i].z, acc[i][j][3] + b4[i].w);
        *(float4*)&out[(long)node * D_ + f0] = o;
      }
    }
  }
}

// ---------------------------------------------------------------------------
// Fused update MLP with residual: out = out + mlp(out). 64-node tile.
// ---------------------------------------------------------------------------
__global__ __launch_bounds__(256) void k_update(
    const unsigned short* __restrict__ wt_u1, const float* __restrict__ ub1,
    const unsigned short* __restrict__ wt_u2, const float* __restrict__ ub2,
    const unsigned short* __restrict__ wt_u3, const float* __restrict__ ub3,
    float* __restrict__ out)
{
  __shared__ __align__(16) unsigned short bufA[64 * 72];
  __shared__ __align__(16) unsigned short bufB[64 * 136];

  const int t = threadIdx.x;
  const int node0 = blockIdx.x * 64;
  const int lane = t & 63;
  const int wr = t >> 6;
  const int l16 = lane & 15, kg = lane >> 4;

  // ---- stage h (fp32 out) -> bf16 bufB ----
  #pragma unroll
  for (int i = 0; i < 8; ++i) {
    const int g = t + 256 * i;
    const int row = g >> 5;          // 32 float4 per row
    const int kc  = g & 31;
    const int node = node0 + row;
    float4 xv = (node < N_) ? ((const float4*)out)[(long)node * 32 + kc]
                            : make_float4(0.f, 0.f, 0.f, 0.f);
    uint2 p;
    p.x = pk2(xv.x, xv.y);
    p.y = pk2(xv.z, xv.w);
    *(uint2*)&bufB[row * 136 + kc * 4] = p;
  }
  __syncthreads();

  f32x4 acc[2][4];

  // ---- u1: K=128 -> M=64, relu, to bufA ----
  gemm_frag64<128, 64>(bufB, wt_u1, acc, wr, l16, kg);
  acc_to_lds64<64, true, 72>(bufA, acc, ub1, wr, l16, kg);
  __syncthreads();

  // ---- u2: K=64 -> M=128, relu, to bufB (h dead after u1) ----
  gemm_frag64<64, 128>(bufA, wt_u2, acc, wr, l16, kg);
  acc_to_lds64<128, true, 136>(bufB, acc, ub2, wr, l16, kg);
  __syncthreads();

  // ---- u3: K=128 -> M=128 + bias + residual(out) -> out ----
  gemm_frag64<128, 128>(bufB, wt_u3, acc, wr, l16, kg);
  {
    float4 b4[2];
    #pragma unroll
    for (int i = 0; i < 2; ++i)
      b4[i] = *(const float4*)&ub3[(wr * 2 + i) * 16 + kg * 4];
    #pragma unroll
    for (int j = 0; j < 4; ++j) {
      const int node = node0 + j * 16 + l16;
      if (node >= N_) continue;
      #pragma unroll
      for (int i = 0; i < 2; ++i) {
        const int f0 = (wr * 2 + i) * 16 + kg * 4;
        const float4 r = *(const float4*)&out[(long)node * D_ + f0];
        float4 o = make_float4(acc[i][j][0] + b4[i].x + r.x,
                               acc[i][j][1] + b4[i].y + r.y,
                               acc[i][j][2] + b4[i].z + r.z,
                               acc[i][j][3] + b4[i].w + r.w);
        *(float4*)&out[(long)node * D_ + f0] = o;
      }
    }
  }
}

// ---------------------------------------------------------------------------
// Max-free attention (R8-proven shape): one node per 32-lane half
// (grid*8 == N_ exactly, no guards). Lane owns 4 channels; 8-lane DPP reduce
// per head; 2 edges per iteration; split K/V buffers (uint2 loads = max
// independent outstanding requests); data prefetch 1 deep, index 2 deep.
// ---------------------------------------------------------------------------
__global__ __launch_bounds__(256) void k_attn(
    const int* __restrict__ esrc, const int2* __restrict__ meta,
    const unsigned short* __restrict__ q,
    const unsigned short* __restrict__ kbuf,
    const unsigned short* __restrict__ vbuf,
    float* __restrict__ out)
{
  const int t = threadIdx.x;
  const unsigned node = blockIdx.x * 8 + (t >> 5);   // 12500*8 == N_
  const int c = t & 31;
  // scale * log2(e): scores land directly in exp2 domain
  const float C = 0.17677669529663687f * 1.4426950408889634f;

  const int2 md = meta[node];
  const int start = md.x, cnt = md.y;
  const int end = start + cnt;

  const uint2 qu = *(const uint2*)&q[(node << 7) + 4u * c];
  const float2 q01 = bf2f2(qu.x), q23 = bf2f2(qu.y);
  const float qx0 = q01.x * C, qx1 = q01.y * C;
  const float qx2 = q23.x * C, qx3 = q23.y * C;

  float l = 0.f, a0 = 0.f, a1 = 0.f, a2 = 0.f, a3 = 0.f;

  const int P = (cnt + 1) >> 1;     // 2 edges per iteration
  if (P > 0) {
    bool v1c = (start + 1) < end;
    unsigned i0 = esrc[start];
    unsigned i1 = esrc[v1c ? start + 1 : start];
    uint2 kA = *(const uint2*)&kbuf[((long)i0 << 7) + 4u * c];
    uint2 kB = *(const uint2*)&kbuf[((long)i1 << 7) + 4u * c];
    uint2 wA = *(const uint2*)&vbuf[((long)i0 << 7) + 4u * c];
    uint2 wB = *(const uint2*)&vbuf[((long)i1 << 7) + 4u * c];
    // next-iteration indices
    bool v0n = (start + 2) < end, v1n = (start + 3) < end;
    unsigned i0n = esrc[v0n ? start + 2 : start];
    unsigned i1n = esrc[v1n ? start + 3 : start];

    for (int it = 0;;) {
      const bool more = (it + 1) < P;
      uint2 kAn, kBn, wAn, wBn;
      unsigned i0f = 0, i1f = 0;
      bool v0f = false, v1f = false;
      if (more) {                    // prefetch: data it+1, indices it+2
        kAn = *(const uint2*)&kbuf[((long)i0n << 7) + 4u * c];
        kBn = *(const uint2*)&kbuf[((long)i1n << 7) + 4u * c];
        wAn = *(const uint2*)&vbuf[((long)i0n << 7) + 4u * c];
        wBn = *(const uint2*)&vbuf[((long)i1n << 7) + 4u * c];
        const int ef = start + 2 * (it + 2);
        v0f = ef < end; v1f = (ef + 1) < end;
        i0f = esrc[v0f ? ef : start];
        i1f = esrc[v1f ? ef + 1 : start];
      }

      // ---- compute current 2 edges (edge0 always valid inside loop) ----
      const float2 ka01 = bf2f2(kA.x), ka23 = bf2f2(kA.y);
      const float2 kb01 = bf2f2(kB.x), kb23 = bf2f2(kB.y);
      float sA = fmaf(qx0, ka01.x, fmaf(qx1, ka01.y, fmaf(qx2, ka23.x, qx3 * ka23.y)));
      float sB = fmaf(qx0, kb01.x, fmaf(qx1, kb01.y, fmaf(qx2, kb23.x, qx3 * kb23.y)));
      sA = rowsum8(sA);
      sB = rowsum8(sB);
      const float eA = __builtin_amdgcn_exp2f(sA);
      const float eB = v1c ? __builtin_amdgcn_exp2f(sB) : 0.f;
      const float2 va01 = bf2f2(wA.x), va23 = bf2f2(wA.y);
      const float2 vb01 = bf2f2(wB.x), vb23 = bf2f2(wB.y);
      l += eA + eB;
      a0 = fmaf(eA, va01.x, fmaf(eB, vb01.x, a0));
      a1 = fmaf(eA, va01.y, fmaf(eB, vb01.y, a1));
      a2 = fmaf(eA, va23.x, fmaf(eB, vb23.x, a2));
      a3 = fmaf(eA, va23.y, fmaf(eB, vb23.y, a3));

      if (!more) break;
      ++it;
      kA = kAn; kB = kBn; wA = wAn; wB = wBn;
      v1c = v1n;
      v0n = v0f; v1n = v1f;
      i0n = i0f; i1n = i1f;
    }
  }

  if (l > 0.f) {
    const float inv = 1.0f / l;
    float4* op = (float4*)&out[(node << 7) + 4u * c];
    float4 cv = *op;
    cv.x += a0 * inv;
    cv.y += a1 * inv;
    cv.z += a2 * inv;
    cv.w += a3 * inv;
    *op = cv;
  }
}

// ---------------------------------------------------------------------------
extern "C" void kernel_launch(void* const* d_in, const int* in_sizes, int n_in,
                              void* d_out, int out_size, void* d_ws, size_t ws_size,
                              hipStream_t stream) {
  const float* x   = (const float*)d_in[0];
  const int*   ei  = (const int*)d_in[1];
  const float* pW1 = (const float*)d_in[2];  const float* pb1 = (const float*)d_in[3];
  const float* pW2 = (const float*)d_in[4];  const float* pb2 = (const float*)d_in[5];
  const float* pW3 = (const float*)d_in[6];  const float* pb3 = (const float*)d_in[7];
  const float* uW1 = (const float*)d_in[8];  const float* ub1 = (const float*)d_in[9];
  const float* uW2 = (const float*)d_in[10]; const float* ub2 = (const float*)d_in[11];
  const float* uW3 = (const float*)d_in[12]; const float* ub3 = (const float*)d_in[13];
  const float* qW  = (const float*)d_in[14]; const float* qb  = (const float*)d_in[15];
  const float* kW  = (const float*)d_in[16]; const float* kb  = (const float*)d_in[17];
  const float* vW  = (const float*)d_in[18]; const float* vb  = (const float*)d_in[19];
  const float* sW  = (const float*)d_in[20]; const float* sb  = (const float*)d_in[21];

  float* out = (float*)d_out;
  float* ws  = (float*)d_ws;

  const long ND = (long)N_ * D_;
  // regions (ND floats each): 0=CSR overlay, 1=q, 2=k, 3=v; 4=weights
  unsigned short* q16 = (unsigned short*)(ws + ND);
  unsigned short* k16 = (unsigned short*)(ws + 2 * ND);
  unsigned short* v16 = (unsigned short*)(ws + 3 * ND);

  unsigned short* wtb = (unsigned short*)(ws + 4 * ND);
  unsigned short* wt_p2 = wtb;            // 64x128
  unsigned short* wt_p3 = wtb + 8192;     // 128x128
  unsigned short* wt_q  = wtb + 24576;
  unsigned short* wt_k  = wtb + 40960;
  unsigned short* wt_v  = wtb + 57344;
  unsigned short* wt_s  = wtb + 73728;
  unsigned short* wt_u1 = wtb + 90112;    // 128x64
  unsigned short* wt_u2 = wtb + 98304;    // 64x128
  unsigned short* wt_u3 = wtb + 106496;   // 128x128

  // CSR overlays in region 0
  int* deg  = (int*)ws;
  int* off  = deg + N_;
  int* cur  = off + N_;
  int* esrc = cur + N_;
  int* bsum = esrc + E_;
  int2* meta = (int2*)(bsum + 512);       // 8B-aligned

  const int gT64 = (N_ + 63) / 64;    // 1563

  // --- zero degree histogram (DMA, graph-capturable) ---
  hipMemsetAsync(deg, 0, N_ * sizeof(int), stream);

  // --- weight conversion || degree histogram (block-range fused) ---
  k_wconv_hist<<<WCONV_NB + HIST_NB, 256, 0, stream>>>(
      pW2, pW3, qW, kW, vW, sW, uW1, uW2, uW3, wtb, ei, deg);

  // --- CSR scans ---
  k_scan1 <<<SCAN_NB, 256, 0, stream>>>(deg, off, bsum);
  k_scan23<<<SCAN_NB, 256, 0, stream>>>(off, bsum, cur, deg, meta);

  // --- CSR fill || prep MLP + projections (block-range fused, 2:1) ---
  k_fill_prep<<<3 * gT64, 256, 0, stream>>>(
      ei, cur, esrc,
      x, pW1, pb1, wt_p2, pb2, wt_p3, pb3,
      wt_q, qb, wt_k, kb, wt_v, vb, wt_s, sb,
      q16, k16, v16, out);

  // --- attention (adds onto skip already in out) ---
  k_attn<<<N_ / 8, 256, 0, stream>>>(esrc, meta, q16, k16, v16, out);

  // --- fused update MLP with residual: out = out + mlp(out) ---
  k_update<<<gT64, 256, 0, stream>>>(wt_u1, ub1, wt_u2, ub2, wt_u3, ub3, out);
}